// Round 6
// baseline (228.375 us; speedup 1.0000x reference)
//
#include <hip/hip_runtime.h>
#include <math.h>

#define L 2048
#define DMODEL 512
#define NH 8
#define DH 64
#define NROWS 4096   // B*L

typedef __attribute__((ext_vector_type(4))) float f32x4;
typedef __attribute__((ext_vector_type(8))) short s16x8;

#define MFMA(a, b, c) __builtin_amdgcn_mfma_f32_16x16x32_bf16(a, b, c, 0, 0, 0)

static __device__ __forceinline__ ushort f2b(float f) {
    union { float f; unsigned u; } v; v.f = f;
    unsigned r = v.u + 0x7FFF + ((v.u >> 16) & 1);
    return (ushort)(r >> 16);
}

// ---------- f32 -> bf16 convert (8 elems/thread) ----------
__global__ __launch_bounds__(256)
void cvt_bf16(const float* __restrict__ in, ushort* __restrict__ out, int n8) {
    int i = blockIdx.x * 256 + threadIdx.x;
    if (i < n8) {
        float4 a = *reinterpret_cast<const float4*>(&in[(size_t)i * 8]);
        float4 b = *reinterpret_cast<const float4*>(&in[(size_t)i * 8 + 4]);
        ushort4 o0; o0.x = f2b(a.x); o0.y = f2b(a.y); o0.z = f2b(a.z); o0.w = f2b(a.w);
        ushort4 o1; o1.x = f2b(b.x); o1.y = f2b(b.y); o1.z = f2b(b.z); o1.w = f2b(b.w);
        *reinterpret_cast<ushort4*>(&out[(size_t)i * 8]) = o0;
        *reinterpret_cast<ushort4*>(&out[(size_t)i * 8 + 4]) = o1;
    }
}

// ---------- W (512x512 f32, row-major [k][n]) -> Wt bf16 [n][k] ----------
__global__ __launch_bounds__(256)
void transpose_w(const float* __restrict__ W0, const float* __restrict__ W1,
                 const float* __restrict__ W2, const float* __restrict__ W3,
                 ushort* __restrict__ T0, ushort* __restrict__ T1,
                 ushort* __restrict__ T2, ushort* __restrict__ T3) {
    const int z = blockIdx.z;
    const float* W = z == 0 ? W0 : (z == 1 ? W1 : (z == 2 ? W2 : W3));
    ushort* T = z == 0 ? T0 : (z == 1 ? T1 : (z == 2 ? T2 : T3));
    __shared__ float Ls[64][65];
    const int tid = threadIdx.x;
    const int k0 = blockIdx.y * 64, n0 = blockIdx.x * 64;
    #pragma unroll
    for (int i = 0; i < 4; ++i) {
        int kk = (tid >> 4) + i * 16, n4 = (tid & 15) * 4;
        float4 v = *reinterpret_cast<const float4*>(&W[(size_t)(k0 + kk) * 512 + n0 + n4]);
        Ls[kk][n4] = v.x; Ls[kk][n4 + 1] = v.y; Ls[kk][n4 + 2] = v.z; Ls[kk][n4 + 3] = v.w;
    }
    __syncthreads();
    #pragma unroll
    for (int i = 0; i < 4; ++i) {
        int nn = (tid >> 4) + i * 16, k4 = (tid & 15) * 4;
        ushort4 o;
        o.x = f2b(Ls[k4 + 0][nn]); o.y = f2b(Ls[k4 + 1][nn]);
        o.z = f2b(Ls[k4 + 2][nn]); o.w = f2b(Ls[k4 + 3][nn]);
        *reinterpret_cast<ushort4*>(&T[(size_t)(n0 + nn) * 512 + k0 + k4]) = o;
    }
}

// ---------- bf16 MFMA GEMM: out = A(4096x512) @ Wt^T + bias ----------
// a_f32: A operand is f32 (converted during staging).
// per-z mode from `modes` nibble: 0: f32 row-major out; 1: bf16 scatter
// (B,H,L,DH); 2: bf16 transposed scatter (B,H,DH,L) [V^T].
__global__ __launch_bounds__(256)
void gemm_bf16(const void* __restrict__ A0, const void* __restrict__ A1,
               const void* __restrict__ A2,
               const ushort* __restrict__ W0, const ushort* __restrict__ W1,
               const ushort* __restrict__ W2,
               const float* __restrict__ b0, const float* __restrict__ b1,
               const float* __restrict__ b2,
               void* o0, void* o1, void* o2, int a_f32, int modes) {
    const int z = blockIdx.z;
    const void* A   = z == 0 ? A0 : (z == 1 ? A1 : A2);
    const ushort* Wt = z == 0 ? W0 : (z == 1 ? W1 : W2);
    const float* bias = z == 0 ? b0 : (z == 1 ? b1 : b2);
    void* outp = z == 0 ? o0 : (z == 1 ? o1 : o2);
    const int mode = (modes >> (4 * z)) & 15;

    __shared__ ushort As[128][40];
    __shared__ ushort Bs[64][40];
    const int tid = threadIdx.x;
    const int w = tid >> 6, lane = tid & 63, g = lane >> 4, c = lane & 15;
    const int m0 = blockIdx.y * 128, n0 = blockIdx.x * 64;

    f32x4 acc[2][4];
    #pragma unroll
    for (int rs = 0; rs < 2; ++rs)
        #pragma unroll
        for (int cs = 0; cs < 4; ++cs) acc[rs][cs] = (f32x4){0.f, 0.f, 0.f, 0.f};

    float bsv[4];
    #pragma unroll
    for (int cs = 0; cs < 4; ++cs) bsv[cs] = bias[n0 + 16 * cs + c];

    for (int k0 = 0; k0 < 512; k0 += 32) {
        {
            int row = tid >> 1, kh = (tid & 1) * 16;
            if (a_f32) {
                const float* p = (const float*)A + (size_t)(m0 + row) * 512 + k0 + kh;
                ushort tmp[16];
                #pragma unroll
                for (int q4 = 0; q4 < 4; ++q4) {
                    float4 f = *reinterpret_cast<const float4*>(p + q4 * 4);
                    tmp[q4 * 4 + 0] = f2b(f.x); tmp[q4 * 4 + 1] = f2b(f.y);
                    tmp[q4 * 4 + 2] = f2b(f.z); tmp[q4 * 4 + 3] = f2b(f.w);
                }
                *reinterpret_cast<uint4*>(&As[row][kh]) = *reinterpret_cast<uint4*>(&tmp[0]);
                *reinterpret_cast<uint4*>(&As[row][kh + 8]) = *reinterpret_cast<uint4*>(&tmp[8]);
            } else {
                const ushort* p = (const ushort*)A + (size_t)(m0 + row) * 512 + k0 + kh;
                uint4 x0 = *reinterpret_cast<const uint4*>(p);
                uint4 x1 = *reinterpret_cast<const uint4*>(p + 8);
                *reinterpret_cast<uint4*>(&As[row][kh]) = x0;
                *reinterpret_cast<uint4*>(&As[row][kh + 8]) = x1;
            }
        }
        {
            int n = tid >> 2, kh = (tid & 3) * 8;
            uint4 x = *reinterpret_cast<const uint4*>(&Wt[(size_t)(n0 + n) * 512 + k0 + kh]);
            *reinterpret_cast<uint4*>(&Bs[n][kh]) = x;
        }
        __syncthreads();
        s16x8 af[2], bf[4];
        #pragma unroll
        for (int rs = 0; rs < 2; ++rs)
            af[rs] = *reinterpret_cast<const s16x8*>(&As[32 * w + 16 * rs + c][8 * g]);
        #pragma unroll
        for (int cs = 0; cs < 4; ++cs)
            bf[cs] = *reinterpret_cast<const s16x8*>(&Bs[16 * cs + c][8 * g]);
        #pragma unroll
        for (int rs = 0; rs < 2; ++rs)
            #pragma unroll
            for (int cs = 0; cs < 4; ++cs)
                acc[rs][cs] = MFMA(af[rs], bf[cs], acc[rs][cs]);
        __syncthreads();
    }
    #pragma unroll
    for (int rs = 0; rs < 2; ++rs)
        #pragma unroll
        for (int cs = 0; cs < 4; ++cs)
            #pragma unroll
            for (int r = 0; r < 4; ++r) {
                int row = m0 + 32 * w + 16 * rs + 4 * g + r;
                int n = n0 + 16 * cs + c;
                float v = acc[rs][cs][r] + bsv[cs];
                int bb = row >> 11, l = row & 2047, hh = n >> 6, dh = n & 63;
                if (mode == 0) {
                    ((float*)outp)[(size_t)row * 512 + n] = v;
                } else if (mode == 1) {
                    ((ushort*)outp)[(((size_t)bb * NH + hh) * L + l) * DH + dh] = f2b(v);
                } else {
                    ((ushort*)outp)[(((size_t)bb * NH + hh) * DH + dh) * L + l] = f2b(v);
                }
            }
}

// ---------- fused relative attention: two-pass, barrier-free main loops ----
// One wg per (bh, 32-row i-block); each WAVE independently owns 32-col tiles
// t = w, w+4, ...  Pass A: softmax denominators in registers. One merge.
// Pass B: recompute S, write FINAL normalized weights (LDS-staged, coalesced)
// and accumulate O = P_norm @ V.  No rescale kernel, no extra global traffic.
__global__ __launch_bounds__(256, 4)
void attn(const ushort* __restrict__ qws, const ushort* __restrict__ kws,
          const ushort* __restrict__ vtg, const ushort* __restrict__ Ebf,
          float* __restrict__ attnw, ushort* __restrict__ ows) {
    __shared__ float Wsc[4][32][68];   // per-wave scratch: Ps[32][36]+Pw | Ored
    __shared__ float lred[4][32];
    __shared__ float linvs[32];

    const int tid = threadIdx.x;
    const int w = tid >> 6, lane = tid & 63, g = lane >> 4, c = lane & 15;
    const int bid = blockIdx.x;
    const int bh = bid & 15;
    const int ib = 63 - (bid >> 4);         // heavy-first
    const int b = bh >> 3, h = bh & 7;
    const int i0 = ib * 32;
    const int nt = ib + 1;                  // 32-col tiles

    const ushort* qb = qws + (size_t)bh * L * DH;
    const ushort* kb = kws + (size_t)bh * L * DH;
    const ushort* vt = vtg + (size_t)bh * DH * L;
    float* ab = attnw + (size_t)bh * L * L;

    float*  Ps = &Wsc[w][0][0];                    // [32][36] f32 (16B-aligned rows)
    ushort* Pw = (ushort*)(Ps + 32 * 36);          // [32][40] bf16

    s16x8 aq[2][2];
    #pragma unroll
    for (int rs = 0; rs < 2; ++rs)
        #pragma unroll
        for (int ks = 0; ks < 2; ++ks)
            aq[rs][ks] = *reinterpret_cast<const s16x8*>(
                qb + (size_t)(i0 + 16 * rs + c) * DH + 32 * ks + 8 * g);

    // S tile (32 x 32 at j0): rel strip + QK^T, masked (-1e30), /8. No barrier.
    auto computeS = [&](int j0, float (&sv)[2][2][4]) {
        const int rbase = L - 32 - i0 + j0;   // E row = rbase + s, s = 31+jl-il
        f32x4 TT[4][2];
        #pragma unroll
        for (int ct = 0; ct < 4; ++ct) {
            int rg = rbase + 16 * ct + c;
            rg = rg > L - 1 ? L - 1 : rg;     // clamped rows only feed masked cols
            s16x8 be0 = *reinterpret_cast<const s16x8*>(Ebf + (size_t)rg * DH + 8 * g);
            s16x8 be1 = *reinterpret_cast<const s16x8*>(Ebf + (size_t)rg * DH + 32 + 8 * g);
            #pragma unroll
            for (int rs = 0; rs < 2; ++rs) {
                f32x4 x = {0.f, 0.f, 0.f, 0.f};
                x = MFMA(aq[rs][0], be0, x);
                x = MFMA(aq[rs][1], be1, x);
                TT[ct][rs] = x;
            }
        }
        float rel[2][2][4];
        #pragma unroll
        for (int r = 0; r < 4; ++r) {
            const int u = c - 4 * g - r;
            const int src = (lane & 48) | ((15 + u) & 15);
            const bool hi = (u >= 1);
            #pragma unroll
            for (int rs = 0; rs < 2; ++rs)
                #pragma unroll
                for (int jh = 0; jh < 2; ++jh) {
                    const int b0 = jh - rs + 1;
                    float va = __shfl(TT[b0][rs][r], src);
                    float vb = __shfl(TT[b0 + 1][rs][r], src);
                    rel[rs][jh][r] = hi ? vb : va;
                }
        }
        s16x8 bk[2][2];
        #pragma unroll
        for (int jh = 0; jh < 2; ++jh)
            #pragma unroll
            for (int ks = 0; ks < 2; ++ks)
                bk[jh][ks] = *reinterpret_cast<const s16x8*>(
                    kb + (size_t)(j0 + 16 * jh + c) * DH + 32 * ks + 8 * g);
        #pragma unroll
        for (int rs = 0; rs < 2; ++rs)
            #pragma unroll
            for (int jh = 0; jh < 2; ++jh) {
                f32x4 x = {0.f, 0.f, 0.f, 0.f};
                x = MFMA(aq[rs][0], bk[jh][0], x);
                x = MFMA(aq[rs][1], bk[jh][1], x);
                #pragma unroll
                for (int r = 0; r < 4; ++r) {
                    const int il = 16 * rs + 4 * g + r;
                    const int jl = 16 * jh + c;
                    float s = (x[r] + rel[rs][jh][r]) * 0.125f;
                    sv[rs][jh][r] = (j0 + jl <= i0 + il) ? s : -1.0e30f;
                }
            }
    };

    // ---------------- Pass A: denominators only ----------------
    float lsum[2][4] = {};
    for (int t = w; t < nt; t += 4) {
        float sv[2][2][4];
        computeS(t * 32, sv);
        #pragma unroll
        for (int rs = 0; rs < 2; ++rs)
            #pragma unroll
            for (int jh = 0; jh < 2; ++jh)
                #pragma unroll
                for (int r = 0; r < 4; ++r)
                    lsum[rs][r] += __expf(sv[rs][jh][r]);
    }
    #pragma unroll
    for (int rs = 0; rs < 2; ++rs)
        #pragma unroll
        for (int r = 0; r < 4; ++r) {
            float s = lsum[rs][r];
            s += __shfl_xor(s, 1); s += __shfl_xor(s, 2);
            s += __shfl_xor(s, 4); s += __shfl_xor(s, 8);
            if (c == 0) lred[w][16 * rs + 4 * g + r] = s;
        }
    __syncthreads();
    if (tid < 32)
        linvs[tid] = 1.0f / (lred[0][tid] + lred[1][tid] + lred[2][tid] + lred[3][tid]);
    __syncthreads();
    float myi[2][4];
    #pragma unroll
    for (int rs = 0; rs < 2; ++rs)
        #pragma unroll
        for (int r = 0; r < 4; ++r)
            myi[rs][r] = linvs[16 * rs + 4 * g + r];

    // ---------------- Pass B: final weights + PV ----------------
    f32x4 O[2][4];
    #pragma unroll
    for (int rs = 0; rs < 2; ++rs)
        #pragma unroll
        for (int cs = 0; cs < 4; ++cs) O[rs][cs] = (f32x4){0.f, 0.f, 0.f, 0.f};

    for (int t = w; t < nt; t += 4) {
        const int j0 = t * 32;
        float sv[2][2][4];
        computeS(j0, sv);
        #pragma unroll
        for (int rs = 0; rs < 2; ++rs)
            #pragma unroll
            for (int jh = 0; jh < 2; ++jh)
                #pragma unroll
                for (int r = 0; r < 4; ++r) {
                    const int il = 16 * rs + 4 * g + r;
                    const int jl = 16 * jh + c;
                    float p = __expf(sv[rs][jh][r]) * myi[rs][r];
                    Ps[il * 36 + jl] = p;
                    Pw[il * 40 + jl] = f2b(p);
                }
        {   // coalesced final-weight write: 32x32 f32 tile, 128 B per row
            const int row = lane >> 1, cb = (lane & 1) * 16;
            float* dst = &ab[(size_t)(i0 + row) * L + j0 + cb];
            const float* srcp = &Ps[row * 36 + cb];
            #pragma unroll
            for (int e = 0; e < 4; ++e)
                *reinterpret_cast<float4*>(dst + 4 * e) =
                    *reinterpret_cast<const float4*>(srcp + 4 * e);
        }
        s16x8 pa[2];
        #pragma unroll
        for (int rs2 = 0; rs2 < 2; ++rs2)
            pa[rs2] = *reinterpret_cast<const s16x8*>(&Pw[(16 * rs2 + c) * 40 + 8 * g]);
        #pragma unroll
        for (int cs = 0; cs < 4; ++cs) {
            s16x8 vtb = *reinterpret_cast<const s16x8*>(
                vt + (size_t)(16 * cs + c) * L + j0 + 8 * g);
            #pragma unroll
            for (int rs2 = 0; rs2 < 2; ++rs2)
                O[rs2][cs] = MFMA(pa[rs2], vtb, O[rs2][cs]);
        }
    }

    // ---------------- O merge across waves (O already normalized) ----------
    #pragma unroll
    for (int rs2 = 0; rs2 < 2; ++rs2)
        #pragma unroll
        for (int cs = 0; cs < 4; ++cs)
            #pragma unroll
            for (int r = 0; r < 4; ++r)
                Wsc[w][16 * rs2 + 4 * g + r][16 * cs + c] = O[rs2][cs][r];
    __syncthreads();
    {
        const int i = tid >> 3, d8 = (tid & 7) * 8;
        ushort o[8];
        #pragma unroll
        for (int e = 0; e < 8; ++e) {
            float a = Wsc[0][i][d8 + e] + Wsc[1][i][d8 + e]
                    + Wsc[2][i][d8 + e] + Wsc[3][i][d8 + e];
            o[e] = f2b(a);
        }
        *reinterpret_cast<uint4*>(
            &ows[((size_t)b * L + i0 + i) * DMODEL + h * DH + d8]) =
            *reinterpret_cast<const uint4*>(&o[0]);
    }

    // ---------------- zero-fill masked region ----------------
    {
        const int row = tid >> 3, cj = (tid & 7) * 4;
        const float4 z = make_float4(0.f, 0.f, 0.f, 0.f);
        float* rowp = &ab[(size_t)(i0 + row) * L];
        for (int j0z = nt * 32; j0z < L; j0z += 32)
            *reinterpret_cast<float4*>(rowp + j0z + cj) = z;
    }
}

extern "C" void kernel_launch(void* const* d_in, const int* in_sizes, int n_in,
                              void* d_out, int out_size, void* d_ws, size_t ws_size,
                              hipStream_t stream) {
    const float* q_in = (const float*)d_in[0];
    const float* k_in = (const float*)d_in[1];
    const float* v_in = (const float*)d_in[2];
    const float* Wq  = (const float*)d_in[4];
    const float* bq  = (const float*)d_in[5];
    const float* Wk  = (const float*)d_in[6];
    const float* bk  = (const float*)d_in[7];
    const float* Wv  = (const float*)d_in[8];
    const float* bv  = (const float*)d_in[9];
    const float* Wfc = (const float*)d_in[10];
    const float* bfc = (const float*)d_in[11];
    const float* E   = (const float*)d_in[12];

    float* out0  = (float*)d_out;                        // (B,L,D) f32
    float* attnw = out0 + (size_t)2 * L * DMODEL;        // (B,H,L,L) f32

    const size_t NA = (size_t)NROWS * DMODEL;            // 2,097,152
    ushort* ws = (ushort*)d_ws;
    ushort* Ebf  = ws;                                   // 131072
    ushort* Wqt  = Ebf + (size_t)L * DH;
    ushort* Wkt  = Wqt + 262144;
    ushort* Wvt  = Wkt + 262144;
    ushort* Wfct = Wvt + 262144;
    ushort* qws  = Wfct + 262144;
    ushort* kws  = qws + NA;
    ushort* vtg  = kws + NA;                             // (B,H,DH,L) bf16
    ushort* ows  = vtg + NA;

    cvt_bf16<<<dim3(64), 256, 0, stream>>>(E, Ebf, (int)(L * DH / 8));
    transpose_w<<<dim3(8, 8, 4), 256, 0, stream>>>(Wq, Wk, Wv, Wfc, Wqt, Wkt, Wvt, Wfct);
    // q, k -> (B,H,L,DH); v -> transposed (B,H,DH,L)
    gemm_bf16<<<dim3(8, 32, 3), 256, 0, stream>>>(q_in, k_in, v_in, Wqt, Wkt, Wvt,
                                                  bq, bk, bv, qws, kws, vtg,
                                                  1, 0x211);
    attn<<<dim3(1024), 256, 0, stream>>>(qws, kws, vtg, Ebf, attnw, ows);
    gemm_bf16<<<dim3(8, 32, 1), 256, 0, stream>>>(ows, ows, ows, Wfct, Wfct, Wfct,
                                                  bfc, bfc, bfc, out0, out0, out0,
                                                  0, 0x0);
}